// Round 6
// baseline (32.168 us; speedup 1.0000x reference)
//
#include <hip/hip_runtime.h>
#include <math.h>

#define B_   4
#define C_   32
#define H_   128
#define W_   128
#define HW_  (H_ * W_)
#define PAD_ 4
#define TW   16
#define TH   8
#define RW   24               /* TW + 8 */
#define RH   16               /* TH + 8 */
#define NPIX (RW * RH)        /* 384 */
#define SPC  5                /* pixel stride in 16B chunks (conflict-free) */
#define NSLOT (NPIX * SPC)    /* 1920 */

typedef _Float16 h2 __attribute__((ext_vector_type(2)));
typedef _Float16 h8 __attribute__((ext_vector_type(8)));
union h8v { h8 v; h2 h[4]; uint4 u; };

__device__ __forceinline__ float fdot2(h2 a, h2 b, float c) {
    return __builtin_amdgcn_fdot2(a, b, c, false);
}
__device__ __forceinline__ h2 shfl_xor_h2(h2 v, int m) {
    union { h2 h; int i; } u; u.h = v;
    u.i = __shfl_xor(u.i, m, 64);
    return u.h;
}

// ---- Kernel A: normalize + pack q,k: f32 [B][C][H][W] -> f16 [2][B*HW][32] ----
__global__ __launch_bounds__(256)
void pack_norm(const float* __restrict__ q, const float* __restrict__ k,
               uint4* __restrict__ ws) {
    const int gid   = blockIdx.x * 256 + threadIdx.x;   // 0 .. 2*B*HW-1
    const int which = (gid >= B_ * HW_);
    const int pix   = which ? gid - B_ * HW_ : gid;
    const int b     = pix >> 14;          // / HW_
    const int hw    = pix & (HW_ - 1);
    const float* src = (which ? k : q) + (size_t)b * C_ * HW_ + hw;

    float v[C_];
    float ss = 0.f;
    #pragma unroll
    for (int c = 0; c < C_; ++c) { v[c] = src[c * HW_]; ss += v[c] * v[c]; }
    const float inv = 1.f / fmaxf(sqrtf(ss), 1e-6f);

    h8v o[4];
    #pragma unroll
    for (int i = 0; i < 4; ++i) {
        #pragma unroll
        for (int j = 0; j < 8; ++j) o[i].v[j] = (_Float16)(v[i * 8 + j] * inv);
    }
    uint4* dst = ws + (size_t)gid * 4;
    #pragma unroll
    for (int i = 0; i < 4; ++i) dst[i] = o[i].u;
}

// ---- Kernel B: windowed softmax aggregation ----
__global__ __launch_bounds__(256, 2)
void aggregate(const uint4* __restrict__ wsq, const uint4* __restrict__ wsk,
               float* __restrict__ out) {
    __shared__ h8 lds[NSLOT];   // 30720 B

    const int tid = threadIdx.x;
    const int x0  = blockIdx.x * TW;
    const int y0  = blockIdx.y * TH;
    const int b   = blockIdx.z;

    // ---- Stage packed normalized k region (zero halo) into LDS ----
    #pragma unroll
    for (int r = 0; r < 8; ++r) {
        const int slot = r * 256 + tid;
        if (slot < NSLOT) {
            const int pix = slot / 5;
            const int ch  = slot - 5 * pix;
            if (ch < 4) {
                const int ry = pix / RW;
                const int rx = pix - ry * RW;
                const int gy = y0 - PAD_ + ry;
                const int gx = x0 - PAD_ + rx;
                uint4 val = {0u, 0u, 0u, 0u};
                if (gy >= 0 && gy < H_ && gx >= 0 && gx < W_)
                    val = wsk[((size_t)(b * HW_ + gy * W_ + gx)) * 4 + ch];
                reinterpret_cast<uint4*>(lds)[slot] = val;
            }
        }
    }

    // ---- Thread mapping: vertical pixel pair + row subset ----
    const int sub    = tid & 3;
    const int pairid = tid >> 2;          // 0..63
    const int pcol   = pairid & 15;
    const int prow   = pairid >> 4;       // 0..3
    const int prow2  = prow * 2;
    const int py0    = y0 + prow2;
    const int py1    = py0 + 1;
    const int pxx    = x0 + pcol;

    // Full packed q for both pixels (8 x dwordx4; L1/L2-served)
    h8v qv0[4], qv1[4];
    {
        const uint4* qp0 = wsq + ((size_t)(b * HW_ + py0 * W_ + pxx)) * 4;
        const uint4* qp1 = wsq + ((size_t)(b * HW_ + py1 * W_ + pxx)) * 4;
        #pragma unroll
        for (int i = 0; i < 4; ++i) { qv0[i].u = qp0[i]; qv1[i].u = qp1[i]; }
    }

    // Row subset: sub0 -> j {0,1,2}, sub1 -> {3,4}, sub2 -> {5,6}, sub3 -> {7,8,9}
    const int jstart = (sub == 0) ? 0 : (sub == 1) ? 3 : (sub == 2) ? 5 : 7;
    const int nact   = (sub == 1 || sub == 2) ? 2 : 3;
    float f0[3], f1[3];
    #pragma unroll
    for (int s = 0; s < 3; ++s) {
        const int j = jstart + s;
        const bool act = (s < nact);
        f0[s] = (act && j <= 8) ? 1.f : 0.f;   // row j serves px0 (dy = j)
        f1[s] = (act && j >= 1) ? 1.f : 0.f;   // row j serves px1 (dy = j-1)
    }

    __syncthreads();

    const float invT = 1.0f / 0.07f;
    float l0 = 0.f, l1 = 0.f;
    h2 acc0[16], acc1[16];
    #pragma unroll
    for (int u = 0; u < 16; ++u) { acc0[u] = (h2)(_Float16)0.f; acc1[u] = (h2)(_Float16)0.f; }

    #pragma unroll
    for (int s = 0; s < 3; ++s) {
        const int j = jstart + s;
        const float m0 = f0[s], m1 = f1[s];
        const h8* rowp = &lds[((prow2 + j) * RW + pcol) * SPC];
        #pragma unroll
        for (int dx = 0; dx < 9; ++dx) {
            const h8* kp = rowp + dx * SPC;
            h8v c0, c1, c2, c3;
            c0.v = kp[0]; c1.v = kp[1]; c2.v = kp[2]; c3.v = kp[3];

            float dA0 = 0.f, dB0 = 0.f, dA1 = 0.f, dB1 = 0.f;
            #pragma unroll
            for (int u = 0; u < 4; ++u) {
                dA0 = fdot2(c0.h[u], qv0[0].h[u], dA0);
                dB0 = fdot2(c1.h[u], qv0[1].h[u], dB0);
                dA0 = fdot2(c2.h[u], qv0[2].h[u], dA0);
                dB0 = fdot2(c3.h[u], qv0[3].h[u], dB0);
                dA1 = fdot2(c0.h[u], qv1[0].h[u], dA1);
                dB1 = fdot2(c1.h[u], qv1[1].h[u], dB1);
                dA1 = fdot2(c2.h[u], qv1[2].h[u], dA1);
                dB1 = fdot2(c3.h[u], qv1[3].h[u], dB1);
            }
            const float wg0 = __expf(fmaf(dA0 + dB0, invT, -invT)) * m0;
            const float wg1 = __expf(fmaf(dA1 + dB1, invT, -invT)) * m1;
            l0 += wg0; l1 += wg1;
            const _Float16 w0h = (_Float16)wg0, w1h = (_Float16)wg1;
            const h2 W0 = {w0h, w0h}, W1 = {w1h, w1h};
            #pragma unroll
            for (int u = 0; u < 4; ++u) {
                acc0[u]      = W0 * c0.h[u] + acc0[u];
                acc0[4 + u]  = W0 * c1.h[u] + acc0[4 + u];
                acc0[8 + u]  = W0 * c2.h[u] + acc0[8 + u];
                acc0[12 + u] = W0 * c3.h[u] + acc0[12 + u];
                acc1[u]      = W1 * c0.h[u] + acc1[u];
                acc1[4 + u]  = W1 * c1.h[u] + acc1[4 + u];
                acc1[8 + u]  = W1 * c2.h[u] + acc1[8 + u];
                acc1[12 + u] = W1 * c3.h[u] + acc1[12 + u];
            }
        }
    }

    // ---- Combine partials across the quad (once) ----
    l0 += __shfl_xor(l0, 1, 64); l0 += __shfl_xor(l0, 2, 64);
    l1 += __shfl_xor(l1, 1, 64); l1 += __shfl_xor(l1, 2, 64);
    #pragma unroll
    for (int u = 0; u < 16; ++u) {
        acc0[u] = acc0[u] + shfl_xor_h2(acc0[u], 1);
        acc1[u] = acc1[u] + shfl_xor_h2(acc1[u], 1);
        acc0[u] = acc0[u] + shfl_xor_h2(acc0[u], 2);
        acc1[u] = acc1[u] + shfl_xor_h2(acc1[u], 2);
    }

    // ---- Each thread writes its 8 channels of both pixels ----
    const float il0 = 1.f / l0, il1 = 1.f / l1;
    float* o0 = out + ((size_t)(b * C_ + sub * 8) * H_ + py0) * W_ + pxx;
    float* o1 = out + ((size_t)(b * C_ + sub * 8) * H_ + py1) * W_ + pxx;
    #pragma unroll
    for (int jj = 0; jj < 8; ++jj) {
        const int u = sub * 4 + (jj >> 1);
        o0[jj * HW_] = (float)acc0[u][jj & 1] * il0;
        o1[jj * HW_] = (float)acc1[u][jj & 1] * il1;
    }
}

extern "C" void kernel_launch(void* const* d_in, const int* in_sizes, int n_in,
                              void* d_out, int out_size, void* d_ws, size_t ws_size,
                              hipStream_t stream) {
    const float* q = (const float*)d_in[0];
    const float* k = (const float*)d_in[1];
    float* out = (float*)d_out;
    uint4* ws = (uint4*)d_ws;
    const uint4* wsq = ws;
    const uint4* wsk = ws + (size_t)B_ * HW_ * 4;

    pack_norm<<<dim3(2 * B_ * HW_ / 256), 256, 0, stream>>>(q, k, ws);
    dim3 grid(W_ / TW, H_ / TH, B_);
    aggregate<<<grid, 256, 0, stream>>>(wsq, wsk, out);
}

// Round 7
// 30.368 us; speedup vs baseline: 1.0593x; 1.0593x over previous
//
#include <hip/hip_runtime.h>
#include <math.h>

#define B_   4
#define C_   32
#define H_   128
#define W_   128
#define HW_  (H_ * W_)
#define PAD_ 4
#define TW   16
#define TH   8
#define RW   24               /* TW + 8 */
#define RH   16               /* TH + 8 */
#define NPIX (RW * RH)        /* 384 */
#define SPC  5                /* pixel stride in 16B chunks = 80 B (conflict-free) */
#define NSLOT (NPIX * SPC)    /* 1920 */
#define NTHREADS 512

typedef _Float16 h2 __attribute__((ext_vector_type(2)));
typedef _Float16 h8 __attribute__((ext_vector_type(8)));
union h8v { h8 v; h2 h[4]; uint4 u; };

__device__ __forceinline__ float fdot2(h2 a, h2 b, float c) {
    return __builtin_amdgcn_fdot2(a, b, c, false);
}
__device__ __forceinline__ h2 shfl_xor_h2(h2 v, int m) {
    union { h2 h; int i; } u; u.h = v;
    u.i = __shfl_xor(u.i, m, 64);
    return u.h;
}

// ---- Kernel A: normalize + pack q,k: f32 [B][C][H][W] -> f16 [2][B*HW][32] ----
__global__ __launch_bounds__(256)
void pack_norm(const float* __restrict__ q, const float* __restrict__ k,
               uint4* __restrict__ ws) {
    const int gid   = blockIdx.x * 256 + threadIdx.x;   // 0 .. 2*B*HW-1
    const int which = (gid >= B_ * HW_);
    const int pix   = which ? gid - B_ * HW_ : gid;
    const int b     = pix >> 14;          // / HW_
    const int hw    = pix & (HW_ - 1);
    const float* src = (which ? k : q) + (size_t)b * C_ * HW_ + hw;

    float v[C_];
    float ss = 0.f;
    #pragma unroll
    for (int c = 0; c < C_; ++c) { v[c] = src[c * HW_]; ss += v[c] * v[c]; }
    const float inv = 1.f / fmaxf(sqrtf(ss), 1e-6f);

    h8v o[4];
    #pragma unroll
    for (int i = 0; i < 4; ++i) {
        #pragma unroll
        for (int j = 0; j < 8; ++j) o[i].v[j] = (_Float16)(v[i * 8 + j] * inv);
    }
    uint4* dst = ws + (size_t)gid * 4;
    #pragma unroll
    for (int i = 0; i < 4; ++i) dst[i] = o[i].u;
}

// ---- Kernel B: windowed softmax aggregation (position-split, VGPR-light) ----
__global__ __launch_bounds__(NTHREADS, 4)
void aggregate(const uint4* __restrict__ wsq, const uint4* __restrict__ wsk,
               float* __restrict__ out) {
    __shared__ h8 lds[NSLOT];   // 30720 B

    const int tid = threadIdx.x;
    const int x0  = blockIdx.x * TW;
    const int y0  = blockIdx.y * TH;
    const int b   = blockIdx.z;

    // ---- Stage packed normalized k region (zero halo) into LDS: pure uint4 copy ----
    #pragma unroll
    for (int r = 0; r < 4; ++r) {
        const int slot = r * NTHREADS + tid;
        if (slot < NSLOT) {
            const int pix = slot / 5;
            const int ch  = slot - 5 * pix;
            if (ch < 4) {
                const int ry = pix / RW;
                const int rx = pix - ry * RW;
                const int gy = y0 - PAD_ + ry;
                const int gx = x0 - PAD_ + rx;
                uint4 val = {0u, 0u, 0u, 0u};
                if (gy >= 0 && gy < H_ && gx >= 0 && gx < W_)
                    val = wsk[((size_t)(b * HW_ + gy * W_ + gx)) * 4 + ch];
                reinterpret_cast<uint4*>(lds)[slot] = val;
            }
        }
    }

    // ---- This thread: pixel px, position-subset sub (p = 4i + sub) ----
    const int px  = tid >> 2;
    const int sub = tid & 3;
    const int tx  = px & (TW - 1);
    const int ty  = px >> 4;
    const int h   = y0 + ty;
    const int w   = x0 + tx;

    // Packed normalized q: 4 x dwordx4 (no normalize needed)
    h8v qv[4];
    {
        const uint4* qp = wsq + ((size_t)(b * HW_ + h * W_ + w)) * 4;
        #pragma unroll
        for (int i = 0; i < 4; ++i) qv[i].u = qp[i];
    }

    __syncthreads();

    const float invT = 1.0f / 0.07f;
    float l = 0.f;
    h2 acc[16];
    #pragma unroll
    for (int u = 0; u < 16; ++u) acc[u] = (h2)(_Float16)0.f;

    #pragma unroll
    for (int i = 0; i < 21; ++i) {
        const int p = i * 4 + sub;
        if (p <= 80) {
            const int dy = (p * 57) >> 9;    // floor(p/9), p in [0,80]
            const int dx = p - dy * 9;
            const h8* kp = &lds[((ty + dy) * RW + (tx + dx)) * SPC];
            h8v kk[4];
            kk[0].v = kp[0]; kk[1].v = kp[1]; kk[2].v = kp[2]; kk[3].v = kp[3];

            float dA = 0.f, dB = 0.f, dC = 0.f, dD = 0.f;
            #pragma unroll
            for (int u = 0; u < 4; ++u) {
                dA = fdot2(kk[0].h[u], qv[0].h[u], dA);
                dB = fdot2(kk[1].h[u], qv[1].h[u], dB);
                dC = fdot2(kk[2].h[u], qv[2].h[u], dC);
                dD = fdot2(kk[3].h[u], qv[3].h[u], dD);
            }
            const float dot = (dA + dB) + (dC + dD);
            const float wg = __expf(fmaf(dot, invT, -invT));  // exp(sim - 1/T)
            l += wg;
            const _Float16 wh = (_Float16)wg;
            const h2 wgh = {wh, wh};
            #pragma unroll
            for (int u = 0; u < 4; ++u) {
                acc[u]      = wgh * kk[0].h[u] + acc[u];       // v_pk_fma_f16
                acc[4 + u]  = wgh * kk[1].h[u] + acc[4 + u];
                acc[8 + u]  = wgh * kk[2].h[u] + acc[8 + u];
                acc[12 + u] = wgh * kk[3].h[u] + acc[12 + u];
            }
        }
    }

    // ---- Combine the 4 partials across the pixel's thread quad ----
    l += __shfl_xor(l, 1, 64);
    #pragma unroll
    for (int u = 0; u < 16; ++u) acc[u] = acc[u] + shfl_xor_h2(acc[u], 1);
    l += __shfl_xor(l, 2, 64);
    #pragma unroll
    for (int u = 0; u < 16; ++u) acc[u] = acc[u] + shfl_xor_h2(acc[u], 2);

    // ---- Each thread writes its 8 channels ----
    const float invl = 1.f / l;
    float* po = out + ((size_t)(b * C_ + sub * 8) * H_ + h) * W_ + w;
    #pragma unroll
    for (int j = 0; j < 8; ++j) {
        const int u = sub * 4 + (j >> 1);
        po[j * HW_] = (float)acc[u][j & 1] * invl;
    }
}

extern "C" void kernel_launch(void* const* d_in, const int* in_sizes, int n_in,
                              void* d_out, int out_size, void* d_ws, size_t ws_size,
                              hipStream_t stream) {
    const float* q = (const float*)d_in[0];
    const float* k = (const float*)d_in[1];
    float* out = (float*)d_out;
    uint4* ws = (uint4*)d_ws;
    const uint4* wsq = ws;
    const uint4* wsk = ws + (size_t)B_ * HW_ * 4;

    pack_norm<<<dim3(2 * B_ * HW_ / 256), 256, 0, stream>>>(q, k, ws);
    dim3 grid(W_ / TW, H_ / TH, B_);
    aggregate<<<grid, NTHREADS, 0, stream>>>(wsq, wsk, out);
}

// Round 8
// 26.577 us; speedup vs baseline: 1.2103x; 1.1426x over previous
//
#include <hip/hip_runtime.h>
#include <math.h>

#define B_   4
#define C_   32
#define H_   128
#define W_   128
#define HW_  (H_ * W_)
#define PAD_ 4
#define TW   16
#define TH   8
#define RW   24               /* TW + 8 */
#define RH   16               /* TH + 8 */
#define NPIX (RW * RH)        /* 384 */
#define SPC  5                /* pixel stride in 16B chunks = 80 B (conflict-free) */
#define NSLOT (NPIX * SPC)    /* 1920 */
#define NTHREADS 512          /* 4 threads per output pixel, 128 px/block */

typedef _Float16 h2 __attribute__((ext_vector_type(2)));
typedef _Float16 h8 __attribute__((ext_vector_type(8)));
union h8v { h8 v; h2 h[4]; uint4 u; };

__device__ __forceinline__ float fdot2(h2 a, h2 b, float c) {
    return __builtin_amdgcn_fdot2(a, b, c, false);
}
__device__ __forceinline__ h2 shfl_xor_h2(h2 v, int m) {
    union { h2 h; int i; } u; u.h = v;
    u.i = __shfl_xor(u.i, m, 64);
    return u.h;
}

__global__ __launch_bounds__(NTHREADS, 4)
void soft_shift_align(const float* __restrict__ q,
                      const float* __restrict__ k,
                      float* __restrict__ out) {
    __shared__ h8 lds[NSLOT];   // 30720 B

    const int tid = threadIdx.x;
    const int x0  = blockIdx.x * TW;
    const int y0  = blockIdx.y * TH;
    const int b   = blockIdx.z;

    const float* kb = k + (size_t)b * C_ * HW_;
    const float* qb = q + (size_t)b * C_ * HW_;

    // ---- Stage normalized key region (zero halo) into LDS as packed f16 ----
    if (tid < NPIX) {
        const int ry = tid / RW;
        const int rx = tid - ry * RW;
        const int gy = y0 - PAD_ + ry;
        const int gx = x0 - PAD_ + rx;
        h8v o[4];
        if (gy >= 0 && gy < H_ && gx >= 0 && gx < W_) {
            float v[C_];
            float ss = 0.f;
            const float* p = kb + gy * W_ + gx;
            #pragma unroll
            for (int c = 0; c < C_; ++c) { v[c] = p[c * HW_]; ss += v[c] * v[c]; }
            const float inv = 1.f / fmaxf(sqrtf(ss), 1e-6f);
            #pragma unroll
            for (int i = 0; i < 4; ++i)
                #pragma unroll
                for (int j = 0; j < 8; ++j) o[i].v[j] = (_Float16)(v[i * 8 + j] * inv);
        } else {
            #pragma unroll
            for (int i = 0; i < 4; ++i) o[i].v = (h8)(_Float16)0.f;
        }
        uint4* dst = reinterpret_cast<uint4*>(lds) + tid * SPC;
        #pragma unroll
        for (int i = 0; i < 4; ++i) dst[i] = o[i].u;
    }

    // ---- This thread: pixel px, position-subset sub (p = 4i + sub) ----
    const int px  = tid >> 2;
    const int sub = tid & 3;
    const int tx  = px & (TW - 1);
    const int ty  = px >> 4;
    const int h   = y0 + ty;
    const int w   = x0 + tx;

    // Full normalized query in registers (L1/L2-served; 4x redundant within quad)
    h8v qv[4];
    {
        float v[C_];
        float ss = 0.f;
        const float* p = qb + h * W_ + w;
        #pragma unroll
        for (int c = 0; c < C_; ++c) { v[c] = p[c * HW_]; ss += v[c] * v[c]; }
        const float inv = 1.f / fmaxf(sqrtf(ss), 1e-6f);
        #pragma unroll
        for (int i = 0; i < 4; ++i)
            #pragma unroll
            for (int j = 0; j < 8; ++j) qv[i].v[j] = (_Float16)(v[i * 8 + j] * inv);
    }

    __syncthreads();

    // ---- Softmax-weighted aggregation; delta-addressed position walk ----
    const float K2 = 20.6099379f;   // (1/0.07) * log2(e)
    float l = 0.f;
    h2 acc[16];
    #pragma unroll
    for (int u = 0; u < 16; ++u) acc[u] = (h2)(_Float16)0.f;

    int dx = sub;                                  // position p = sub: dy=0, dx=sub
    const h8* kp = &lds[(ty * RW + tx + sub) * SPC];

    #pragma unroll
    for (int i = 0; i < 21; ++i) {
        const int p = i * 4 + sub;
        if (p <= 80) {                             // only i==20, sub!=0 masked off
            h8v kk[4];
            kk[0].v = kp[0]; kk[1].v = kp[1]; kk[2].v = kp[2]; kk[3].v = kp[3];

            float dA = 0.f, dB = 0.f, dC = 0.f, dD = 0.f;
            #pragma unroll
            for (int u = 0; u < 4; ++u) {
                dA = fdot2(kk[0].h[u], qv[0].h[u], dA);
                dB = fdot2(kk[1].h[u], qv[1].h[u], dB);
                dC = fdot2(kk[2].h[u], qv[2].h[u], dC);
                dD = fdot2(kk[3].h[u], qv[3].h[u], dD);
            }
            const float dot = (dA + dB) + (dC + dD);
            const float wg  = exp2f(fmaf(dot, K2, -K2));   // exp((sim-1)/T), in (0,1]
            l += wg;
            const _Float16 wh = (_Float16)wg;
            const h2 wgh = {wh, wh};
            #pragma unroll
            for (int u = 0; u < 4; ++u) {
                acc[u]      = wgh * kk[0].h[u] + acc[u];    // v_pk_fma_f16
                acc[4 + u]  = wgh * kk[1].h[u] + acc[4 + u];
                acc[8 + u]  = wgh * kk[2].h[u] + acc[8 + u];
                acc[12 + u] = wgh * kk[3].h[u] + acc[12 + u];
            }
        }
        if (i < 20) {                              // advance p -> p+4 (2-way delta)
            const bool wrap = (dx >= 5);
            kp += wrap ? (RW - 5) * SPC : 4 * SPC; // 95 or 20 slots (16B units)
            dx  = wrap ? dx - 5 : dx + 4;
        }
    }

    // ---- Combine the 4 partials across the pixel's thread quad ----
    l += __shfl_xor(l, 1, 64);
    #pragma unroll
    for (int u = 0; u < 16; ++u) acc[u] = acc[u] + shfl_xor_h2(acc[u], 1);
    l += __shfl_xor(l, 2, 64);
    #pragma unroll
    for (int u = 0; u < 16; ++u) acc[u] = acc[u] + shfl_xor_h2(acc[u], 2);

    // ---- Each thread writes its 8 channels ----
    const float invl = 1.f / l;
    float* po = out + ((size_t)(b * C_ + sub * 8) * H_ + h) * W_ + w;
    #pragma unroll
    for (int j = 0; j < 8; ++j) {
        const int u = sub * 4 + (j >> 1);
        po[j * HW_] = (float)acc[u][j & 1] * invl;
    }
}

extern "C" void kernel_launch(void* const* d_in, const int* in_sizes, int n_in,
                              void* d_out, int out_size, void* d_ws, size_t ws_size,
                              hipStream_t stream) {
    const float* q = (const float*)d_in[0];
    const float* k = (const float*)d_in[1];
    float* out = (float*)d_out;
    dim3 grid(W_ / TW, H_ / TH, B_);
    soft_shift_align<<<grid, NTHREADS, 0, stream>>>(q, k, out);
}